// Round 11
// baseline (174.696 us; speedup 1.0000x reference)
//
#include <hip/hip_runtime.h>
#include <hip/hip_fp16.h>
#include <math.h>

#define NN      8192
#define LOGN    13
#define ROWS    512
#define NT      1024
#define NNODES  31
#define EPSF    1e-6f
#define PRUNEF  0.05f
#define SQRT1_2F 0.70710678118654752f
#define PIF      3.14159265358979323f
#define INV_PIF  0.31830988618379067f

typedef unsigned int uint;

// ---------------- fast math ----------------
__device__ __forceinline__ float fast_rcp(float x){ return __builtin_amdgcn_rcpf(x); }
__device__ __forceinline__ float fast_rsq(float x){ return __builtin_amdgcn_rsqf(x); }

__device__ __forceinline__ float tanh_pade(float y){
    y = fminf(3.f, fmaxf(-3.f, y));
    float y2 = y * y;
    float num = y * fmaf(y2, 10.f, 105.f);
    float den = fmaf(y2, 45.f, fmaf(y2 * y2, 1.f, 105.f));
    return num * fast_rcp(den);
}
__device__ __forceinline__ float silu_pade(float h){
    float y = fminf(3.f, fmaxf(-3.f, 0.5f * h));
    float y2 = y * y;
    float num = y * fmaf(y2, 10.f, 105.f);
    float den = fmaf(y2, 45.f, fmaf(y2 * y2, 1.f, 105.f));
    return 0.5f * h * (1.f + num * fast_rcp(den));
}
__device__ __forceinline__ float exp_small(float z){
    return fmaf(z, fmaf(z, fmaf(z, fmaf(z, 0.041666667f, 0.16666667f), 0.5f), 1.f), 1.f);
}
__device__ __forceinline__ float sin_halfpi(float t){
    float t2 = t * t;
    return t * fmaf(t2, fmaf(t2, fmaf(t2, -4.6817541e-3f, 7.96926262e-2f), -6.45964097e-1f), 1.57079632f);
}
__device__ __forceinline__ float cos_halfpi(float t){
    float t2 = t * t;
    return fmaf(t2, fmaf(t2, fmaf(t2, fmaf(t2, 9.1937e-4f, -2.08634807e-2f), 2.53669508e-1f), -1.23370055f), 1.f);
}

__device__ __forceinline__ float fast_atan2f(float y, float x) {
    float ay = fabsf(y), ax = fabsf(x);
    float mx = fmaxf(ax, ay), mn = fminf(ax, ay);
    float a = (mx > 0.f) ? (mn * fast_rcp(mx)) : 0.f;
    bool big = a > 0.4142135679f;
    float t = big ? ((a - 1.f) * fast_rcp(a + 1.f)) : a;
    float z2 = t * t;
    float p = fmaf(8.05374449538e-2f, z2, -1.38776856032e-1f);
    p = fmaf(p, z2, 1.99777106478e-1f);
    p = fmaf(p, z2, -3.33329491539e-1f);
    float r = fmaf(p * z2, t, t);
    if (big) r += 0.78539816339744831f;
    if (ay > ax) r = 1.57079632679489662f - r;
    if (x < 0.f) r = 3.14159265358979323f - r;
    return copysignf(r, y);
}

__device__ __forceinline__ float2 cmul(float2 a, float2 b){
    return make_float2(a.x*b.x - a.y*b.y, a.x*b.y + a.y*b.x);
}
__device__ __forceinline__ float2 cadd(float2 a, float2 b){ return make_float2(a.x+b.x, a.y+b.y); }
__device__ __forceinline__ float2 csub(float2 a, float2 b){ return make_float2(a.x-b.x, a.y-b.y); }

__device__ __forceinline__ uint pack_h2(float2 v){
    __half2 h = __floats2half2_rn(v.x, v.y);
    return __builtin_bit_cast(uint, h);
}
__device__ __forceinline__ float2 unpack_h2(uint u){
    __half2 h = __builtin_bit_cast(__half2, u);
    return make_float2(__low2float(h), __high2float(h));
}

__device__ __forceinline__ void wave_red8(float* a) {
    #pragma unroll
    for (int m = 32; m >= 1; m >>= 1) {
        #pragma unroll
        for (int q = 0; q < 8; ++q) a[q] += __shfl_xor(a[q], m);
    }
}

#define C4C 0.70710678119f

// ---- forward LDS radix-4 stage (levels 2*HH, HH), NT=1024 => 2 chunks ----
template<int HH, int LG>
__device__ __forceinline__ void fwd_r4_stage(float2* sh, int tid) {
    int j = tid & (HH - 1);
    float ang = (-PIF / (2.0f * (float)HH)) * (float)j;
    float s = __sinf(ang), co = __cosf(ang);
    float2 t1 = make_float2(co, s);
    float2 t2 = make_float2(co * co - s * s, 2.f * co * s);
    #pragma unroll
    for (int c = 0; c < 2; ++c) {
        int q = tid + (c << 10);
        int p = ((q >> LG) << (LG + 2)) | j;
        float2 a = sh[p], b = sh[p + HH], cc = sh[p + 2*HH], d = sh[p + 3*HH];
        float2 a1 = cadd(a, cc);
        float2 c1 = cmul(csub(a, cc), t1);
        float2 b1 = cadd(b, d);
        float2 u  = cmul(csub(b, d), t1);
        float2 d1 = make_float2(u.y, -u.x);          // -i*u
        sh[p]        = cadd(a1, b1);
        sh[p + HH]   = cmul(csub(a1, b1), t2);
        sh[p + 2*HH] = cadd(c1, d1);
        sh[p + 3*HH] = cmul(csub(c1, d1), t2);
    }
    __syncthreads();
}

// ---- inverse LDS radix-4 stage (levels H, 2*H) ----
template<int H, int LG>
__device__ __forceinline__ void inv_r4_stage(float2* sh, int tid) {
    int jj = tid & (H - 1);
    float ang = (PIF / (2.0f * (float)H)) * (float)jj;
    float s2 = __sinf(ang), c2 = __cosf(ang);
    float2 t2 = make_float2(c2, s2);
    float2 t1 = make_float2(c2 * c2 - s2 * s2, 2.f * c2 * s2);
    #pragma unroll
    for (int c = 0; c < 2; ++c) {
        int q = tid + (c << 10);
        int p0 = ((q >> LG) << (LG + 2)) | jj;
        float2 a = sh[p0], b = sh[p0 + H], cc = sh[p0 + 2*H], d = sh[p0 + 3*H];
        float2 tb = cmul(t1, b);
        float2 ap = cadd(a, tb), bp2 = csub(a, tb);
        float2 td = cmul(t1, d);
        float2 cp = cadd(cc, td), dp2 = csub(cc, td);
        float2 tc = cmul(t2, cp);
        float2 u  = cmul(t2, dp2);
        float2 iB = make_float2(-u.y, u.x);          // +i*u
        sh[p0]       = cadd(ap, tc);
        sh[p0 + H]   = cadd(bp2, iB);
        sh[p0 + 2*H] = csub(ap, tc);
        sh[p0 + 3*H] = csub(bp2, iB);
    }
    __syncthreads();
}

// ======================= K1: FFT + filter + stats pyramid ==================
__global__ __launch_bounds__(NT, 8) void k_pre(
    const float* __restrict__ x, uint* __restrict__ Lv16,
    float* __restrict__ Se, float* __restrict__ Coh, float* __restrict__ Ent,
    const float* lfg_p, const float* sig_p, const float* hfg_p, const float* cut_p)
{
    __shared__ float2 sh[NN];        // 64KB
    __shared__ float4 wred[16];
    __shared__ float nacc[30 * 4];
    int row = blockIdx.x, tid = threadIdx.x;
    float lfg = *lfg_p, sigma = *sig_p, hfg = *hfg_p, cutoff = *cut_p;

    // ---- load natural-order comb into registers (8 slots) ----
    const float* xr = x + ((size_t)row << LOGN);
    float2 v[8];
    #pragma unroll
    for (int t = 0; t < 8; ++t)
        v[t] = make_float2(xr[tid + (t << 10)], 0.f);

    // ---- register DIF levels: halves 4096, 2048, 1024 ----
    {
        float a0 = -PIF * (1.0f / 4096.0f) * (float)tid;
        float2 w1 = make_float2(__cosf(a0), __sinf(a0));
        float2 w2 = cmul(w1, w1);
        float2 w4 = cmul(w2, w2);
        const float2 K4m[4] = {{1.f,0.f},{C4C,-C4C},{0.f,-1.f},{-C4C,-C4C}};
        #pragma unroll
        for (int t = 0; t < 4; ++t) {
            float2 W = cmul(w1, K4m[t]);
            float2 a = v[t], b = v[t + 4];
            v[t] = cadd(a, b);
            v[t + 4] = cmul(csub(a, b), W);
        }
        #pragma unroll
        for (int t = 0; t < 8; ++t) if (!(t & 2)) {
            float2 W = (t & 1) ? make_float2(w2.y, -w2.x) : w2;
            float2 a = v[t], b = v[t + 2];
            v[t] = cadd(a, b);
            v[t + 2] = cmul(csub(a, b), W);
        }
        #pragma unroll
        for (int t = 0; t < 8; ++t) if (!(t & 1)) {
            float2 a = v[t], b = v[t + 1];
            v[t] = cadd(a, b);
            v[t + 1] = cmul(csub(a, b), w4);
        }
    }

    // ---- LDS: 10 levels = 5 radix-4 stages ----
    #pragma unroll
    for (int t = 0; t < 8; ++t) sh[tid + (t << 10)] = v[t];
    __syncthreads();
    fwd_r4_stage<256, 8>(sh, tid);   // 512,256
    fwd_r4_stage<64, 6>(sh, tid);    // 128,64
    fwd_r4_stage<16, 4>(sh, tid);    // 32,16
    fwd_r4_stage<4, 2>(sh, tid);     // 8,4
    {   // levels 2,1 (no twiddle)
        #pragma unroll
        for (int c = 0; c < 2; ++c) {
            int p = (tid + (c << 10)) << 2;
            float2 a = sh[p], b = sh[p+1], cc = sh[p+2], d = sh[p+3];
            float2 a1 = cadd(a, cc), c1 = csub(a, cc);
            float2 b1 = cadd(b, d);
            float2 u  = csub(b, d);
            float2 d1 = make_float2(u.y, -u.x);
            sh[p]   = cadd(a1, b1);
            sh[p+1] = csub(a1, b1);
            sh[p+2] = cadd(c1, d1);
            sh[p+3] = csub(c1, d1);
        }
        __syncthreads();
    }

    // ---- frequency filter + root stats (comb back to regs) ----
    if (tid < 120) nacc[tid] = 0.f;
    float inv_gs = 1.f / fmaxf(sigma, 0.05f);
    float is2 = 1.f / (sigma * sigma);
    float se = 0.f, slg = 0.f, sux = 0.f, suy = 0.f;
    #pragma unroll
    for (int t = 0; t < 8; ++t) {
        int p = tid + (t << 10);
        int k = (int)(__brev((uint)p) >> 19);
        float fk = (k < NN / 2) ? (float)k : (float)(k - NN);
        float f = fk * (1.0f / (float)NN);
        float r2 = f * f;
        float lfb = 1.f + lfg * __expf(-r2 * is2);
        float radius = sqrtf(r2 + 1e-12f);
        float gate = fast_rcp(1.f + __expf(-(cutoff - radius) * inv_gs));
        float mult = lfb * (hfg + (1.f - hfg) * gate);
        float2 c = sh[p];
        c.x *= mult; c.y *= mult;
        v[t] = c;
        float e = fmaf(c.x, c.x, c.y * c.y);
        se += e;
        slg += e * __logf(fmaxf(e, 1e-30f));
        float inv = fminf(fast_rsq(e), 1e6f);
        sux += c.x * inv; suy += c.y * inv;
    }
    #pragma unroll
    for (int m = 32; m >= 1; m >>= 1) {
        se += __shfl_xor(se, m); slg += __shfl_xor(slg, m);
        sux += __shfl_xor(sux, m); suy += __shfl_xor(suy, m);
    }
    if ((tid & 63) == 0) wred[tid >> 6] = make_float4(se, slg, sux, suy);
    __syncthreads();                       // covers wred + nacc zero
    if (tid == 0) {
        float4 r = wred[0];
        #pragma unroll
        for (int w = 1; w < 16; ++w) {
            r.x += wred[w].x; r.y += wred[w].y; r.z += wred[w].z; r.w += wred[w].w;
        }
        float gx = r.z / (float)NN, gy = r.w / (float)NN;
        float ga = sqrtf(gx * gx + gy * gy);
        float denom = fmaxf(r.x, EPSF);
        Se[row]  = r.x;
        Ent[row] = __logf(denom) - r.y / denom;
        Coh[row] = fminf(ga, 1.f);
    }

    // ---- pyramid splits d0..d2 in registers with fused child stats ----
    {   // d0: stride 4; children g=1 (slots 0-3), g=2 (slots 4-7)
        #pragma unroll
        for (int t = 0; t < 4; ++t) {
            float2 a = v[t], b = v[t + 4];
            v[t]     = make_float2((a.x + b.x) * SQRT1_2F, (a.y + b.y) * SQRT1_2F);
            v[t + 4] = make_float2((a.x - b.x) * SQRT1_2F, (a.y - b.y) * SQRT1_2F);
        }
        float acc[8] = {0,0,0,0,0,0,0,0};
        #pragma unroll
        for (int s = 0; s < 4; ++s) {
            float2 w = v[s];
            float e = fmaf(w.x, w.x, w.y * w.y);
            acc[0] += e; acc[1] += e * __logf(fmaxf(e, 1e-30f));
            float iv = fminf(fast_rsq(e), 1e6f);
            acc[2] += w.x * iv; acc[3] += w.y * iv;
            float2 h = v[s + 4];
            float e2 = fmaf(h.x, h.x, h.y * h.y);
            acc[4] += e2; acc[5] += e2 * __logf(fmaxf(e2, 1e-30f));
            float iv2 = fminf(fast_rsq(e2), 1e6f);
            acc[6] += h.x * iv2; acc[7] += h.y * iv2;
        }
        wave_red8(acc);
        if ((tid & 63) == 0) {
            atomicAdd(&nacc[0], acc[0]); atomicAdd(&nacc[1], acc[1]);
            atomicAdd(&nacc[2], acc[2]); atomicAdd(&nacc[3], acc[3]);
            atomicAdd(&nacc[4], acc[4]); atomicAdd(&nacc[5], acc[5]);
            atomicAdd(&nacc[6], acc[6]); atomicAdd(&nacc[7], acc[7]);
        }
    }
    {   // d1: stride 2; children g=3..6
        #pragma unroll
        for (int t = 0; t < 8; ++t) if (!(t & 2)) {
            float2 a = v[t], b = v[t + 2];
            v[t]     = make_float2((a.x + b.x) * SQRT1_2F, (a.y + b.y) * SQRT1_2F);
            v[t + 2] = make_float2((a.x - b.x) * SQRT1_2F, (a.y - b.y) * SQRT1_2F);
        }
        #pragma unroll
        for (int pr = 0; pr < 2; ++pr) {
            float acc[8] = {0,0,0,0,0,0,0,0};
            #pragma unroll
            for (int s = 0; s < 2; ++s) {
                float2 w = v[4 * pr + s];
                float e = fmaf(w.x, w.x, w.y * w.y);
                acc[0] += e; acc[1] += e * __logf(fmaxf(e, 1e-30f));
                float iv = fminf(fast_rsq(e), 1e6f);
                acc[2] += w.x * iv; acc[3] += w.y * iv;
                float2 h = v[4 * pr + 2 + s];
                float e2 = fmaf(h.x, h.x, h.y * h.y);
                acc[4] += e2; acc[5] += e2 * __logf(fmaxf(e2, 1e-30f));
                float iv2 = fminf(fast_rsq(e2), 1e6f);
                acc[6] += h.x * iv2; acc[7] += h.y * iv2;
            }
            wave_red8(acc);
            if ((tid & 63) == 0) {
                int ga = 3 + 2 * pr, gb = ga + 1;
                atomicAdd(&nacc[(ga-1)*4+0], acc[0]); atomicAdd(&nacc[(ga-1)*4+1], acc[1]);
                atomicAdd(&nacc[(ga-1)*4+2], acc[2]); atomicAdd(&nacc[(ga-1)*4+3], acc[3]);
                atomicAdd(&nacc[(gb-1)*4+0], acc[4]); atomicAdd(&nacc[(gb-1)*4+1], acc[5]);
                atomicAdd(&nacc[(gb-1)*4+2], acc[6]); atomicAdd(&nacc[(gb-1)*4+3], acc[7]);
            }
        }
    }
    {   // d2: stride 1; children g=7..14 (one slot each)
        #pragma unroll
        for (int t = 0; t < 8; ++t) if (!(t & 1)) {
            float2 a = v[t], b = v[t + 1];
            v[t]     = make_float2((a.x + b.x) * SQRT1_2F, (a.y + b.y) * SQRT1_2F);
            v[t + 1] = make_float2((a.x - b.x) * SQRT1_2F, (a.y - b.y) * SQRT1_2F);
        }
        #pragma unroll
        for (int pr = 0; pr < 4; ++pr) {
            float acc[8] = {0,0,0,0,0,0,0,0};
            {
                float2 w = v[2 * pr];
                float e = fmaf(w.x, w.x, w.y * w.y);
                acc[0] = e; acc[1] = e * __logf(fmaxf(e, 1e-30f));
                float iv = fminf(fast_rsq(e), 1e6f);
                acc[2] = w.x * iv; acc[3] = w.y * iv;
                float2 h = v[2 * pr + 1];
                float e2 = fmaf(h.x, h.x, h.y * h.y);
                acc[4] = e2; acc[5] = e2 * __logf(fmaxf(e2, 1e-30f));
                float iv2 = fminf(fast_rsq(e2), 1e6f);
                acc[6] = h.x * iv2; acc[7] = h.y * iv2;
            }
            wave_red8(acc);
            if ((tid & 63) == 0) {
                int ga = 7 + 2 * pr, gb = ga + 1;
                atomicAdd(&nacc[(ga-1)*4+0], acc[0]); atomicAdd(&nacc[(ga-1)*4+1], acc[1]);
                atomicAdd(&nacc[(ga-1)*4+2], acc[2]); atomicAdd(&nacc[(ga-1)*4+3], acc[3]);
                atomicAdd(&nacc[(gb-1)*4+0], acc[4]); atomicAdd(&nacc[(gb-1)*4+1], acc[5]);
                atomicAdd(&nacc[(gb-1)*4+2], acc[6]); atomicAdd(&nacc[(gb-1)*4+3], acc[7]);
            }
        }
    }

    // ---- d3 split (stride 512, cross-thread): via LDS, fused leaf stats ----
    #pragma unroll
    for (int t = 0; t < 8; ++t) sh[tid + (t << 10)] = v[t];
    __syncthreads();
    #pragma unroll
    for (int t = 0; t < 4; ++t) {
        int q = tid + (t << 10);                 // q in [0,4096)
        int p = ((q >> 9) << 10) | (q & 511);
        float2 a = sh[p], b = sh[p + 512];
        float2 lo = make_float2((a.x + b.x) * SQRT1_2F, (a.y + b.y) * SQRT1_2F);
        float2 hi = make_float2((a.x - b.x) * SQRT1_2F, (a.y - b.y) * SQRT1_2F);
        sh[p] = lo; sh[p + 512] = hi;
        float acc[8];
        float e = fmaf(lo.x, lo.x, lo.y * lo.y);
        acc[0] = e; acc[1] = e * __logf(fmaxf(e, 1e-30f));
        float iv = fminf(fast_rsq(e), 1e6f);
        acc[2] = lo.x * iv; acc[3] = lo.y * iv;
        float e2 = fmaf(hi.x, hi.x, hi.y * hi.y);
        acc[4] = e2; acc[5] = e2 * __logf(fmaxf(e2, 1e-30f));
        float iv2 = fminf(fast_rsq(e2), 1e6f);
        acc[6] = hi.x * iv2; acc[7] = hi.y * iv2;
        wave_red8(acc);
        if ((tid & 63) == 0) {
            int ca = (q >> 9) << 1;              // leaf index 0..14 even
            int ia = (14 + ca) * 4;              // g=15+ca -> (g-1)*4
            atomicAdd(&nacc[ia+0], acc[0]); atomicAdd(&nacc[ia+1], acc[1]);
            atomicAdd(&nacc[ia+2], acc[2]); atomicAdd(&nacc[ia+3], acc[3]);
            atomicAdd(&nacc[ia+4], acc[4]); atomicAdd(&nacc[ia+5], acc[5]);
            atomicAdd(&nacc[ia+6], acc[6]); atomicAdd(&nacc[ia+7], acc[7]);
        }
    }
    __syncthreads();
    if (tid < 30) {
        int g = tid + 1;
        float E = nacc[tid * 4 + 0], SL = nacc[tid * 4 + 1];
        float ZX = nacc[tid * 4 + 2], ZY = nacc[tid * 4 + 3];
        float denom = fmaxf(E, EPSF);
        float ent = __logf(denom) - SL / denom;
        int d = 31 - __clz(g + 1);
        float invn = 1.f / (float)(NN >> d);
        float zx = ZX * invn, zy = ZY * invn;
        float ch = fminf(sqrtf(zx * zx + zy * zy), 1.f);
        Se[g * ROWS + row] = E; Coh[g * ROWS + row] = ch; Ent[g * ROWS + row] = ent;
    }

    // ---- store depth-4 leaves packed fp16 from LDS ----
    uint* lrow = Lv16 + ((size_t)row << LOGN);
    #pragma unroll
    for (int t = 0; t < 8; ++t) {
        int k = tid + (t << 10);
        lrow[k] = pack_h2(sh[k]);
    }
}

// ======================= K2: decide (1 block of 512) =======================
__global__ __launch_bounds__(512) void k_decide(
    const float* __restrict__ Se, const float* __restrict__ Coh, const float* __restrict__ Ent,
    int* __restrict__ fFg, int* __restrict__ fPg)
{
    __shared__ float dtmp[3 * NNODES];
    __shared__ int fF[NNODES], fP[NNODES];
    int tid = threadIdx.x;
    float* dcost = dtmp; float* dne = dtmp + NNODES; float* dcm = dtmp + 2 * NNODES;
    int wid = tid >> 6, lane = tid & 63;
    for (int gn = wid; gn < NNODES; gn += 8) {
        float a = 0.f, b = 0.f, cc = 0.f;
        #pragma unroll
        for (int rr = 0; rr < ROWS / 64; ++rr) {
            int r = lane + (rr << 6);
            float ch = Coh[gn * ROWS + r];
            a += Ent[gn * ROWS + r] + 1.f - ch;
            b += Se[gn * ROWS + r];
            cc += ch;
        }
        #pragma unroll
        for (int m = 32; m >= 1; m >>= 1) {
            a += __shfl_xor(a, m); b += __shfl_xor(b, m); cc += __shfl_xor(cc, m);
        }
        if (lane == 0) { dcost[gn] = a / (float)ROWS; dne[gn] = b; dcm[gn] = cc / (float)ROWS; }
    }
    __syncthreads();
    if (tid == 0) {
        float mc[NNODES]; int sel[NNODES]; int act[NNODES];
        for (int gn = NNODES - 1; gn >= 0; --gn) {
            if (gn >= 15) { mc[gn] = dcost[gn]; sel[gn] = 0; }
            else {
                float chc = mc[2 * gn + 1] + mc[2 * gn + 2];
                sel[gn] = (chc < dcost[gn]) ? 1 : 0;
                mc[gn] = fminf(chc, dcost[gn]);
            }
        }
        float total_e = dne[0];
        act[0] = 1;
        for (int gn = 1; gn < NNODES; ++gn) {
            int p = (gn - 1) >> 1;
            act[gn] = act[p] && sel[p];
        }
        for (int gn = 0; gn < NNODES; ++gn) {
            int isleaf = (gn >= 15);
            fF[gn] = (act[gn] && (isleaf || !sel[gn])) ? 1 : 0;
            fP[gn] = ((dne[gn] / total_e < PRUNEF) || (dcm[gn] < PRUNEF)) ? 1 : 0;
        }
    }
    __syncthreads();
    if (tid < NNODES) { fFg[tid] = fF[tid]; fPg[tid] = fP[tid]; }
}

// ======================= median helpers (1024 bins, 1/thread) ==============
__device__ __forceinline__ uint key_of(float2 v) {
    return __float_as_uint(fmaf(v.x, v.x, v.y * v.y));
}

__device__ __forceinline__ uint2 hist_locate1k(
    const uint* hist, int tid, uint r, uint* wsum, uint* selres)
{
    uint s = hist[tid];
    uint sc = s;
    #pragma unroll
    for (int o = 1; o < 64; o <<= 1) {
        uint u = __shfl_up(sc, o);
        if ((tid & 63) >= o) sc += u;
    }
    int wid = tid >> 6;
    if ((tid & 63) == 63) wsum[wid] = sc;
    __syncthreads();
    uint wb = 0;
    #pragma unroll
    for (int w = 0; w < 16; ++w) if (w < wid) wb += wsum[w];
    uint c0 = wb + sc - s;
    if (r >= c0 && r < c0 + s) { selres[0] = (uint)tid; selres[1] = c0; }
    __syncthreads();
    uint2 res = make_uint2(selres[0], selres[1]);
    __syncthreads();
    return res;
}

// 3-level select over dynamic-length sh window (rare path)
__device__ float median_dyn(
    const float2* sh, int nd, int tid, uint* hist, uint* wsum, uint* selres)
{
    uint r1 = (uint)(nd / 2 - 1), r2 = (uint)(nd / 2);
    if (tid < 1024) hist[tid] = 0u;
    __syncthreads();
    for (int i = tid; i < nd; i += NT) atomicAdd(&hist[key_of(sh[i]) >> 21], 1u);
    __syncthreads();
    uint2 A1 = hist_locate1k(hist, tid, r1, wsum, selres);
    uint2 A2 = hist_locate1k(hist, tid, r2, wsum, selres);
    uint va, vb;
    if (A1.x != A2.x) {
        if (tid == 0) { selres[0] = 0u; selres[1] = 0xFFFFFFFFu; }
        __syncthreads();
        for (int i = tid; i < nd; i += NT) {
            uint k = key_of(sh[i]);
            uint b = k >> 21;
            if (b == A1.x) atomicMax(&selres[0], k);
            if (b == A2.x) atomicMin(&selres[1], k);
        }
        __syncthreads();
        va = selres[0]; vb = selres[1];
        __syncthreads();
    } else {
        uint p1 = A1.x;
        if (tid < 1024) hist[tid] = 0u;
        __syncthreads();
        for (int i = tid; i < nd; i += NT) {
            uint k = key_of(sh[i]);
            if ((k >> 21) == p1) atomicAdd(&hist[(k >> 11) & 1023u], 1u);
        }
        __syncthreads();
        uint2 B1 = hist_locate1k(hist, tid, r1 - A1.y, wsum, selres);
        uint2 B2 = hist_locate1k(hist, tid, r2 - A1.y, wsum, selres);
        if (B1.x != B2.x) {
            uint pA = (p1 << 10) | B1.x, pB = (p1 << 10) | B2.x;
            if (tid == 0) { selres[0] = 0u; selres[1] = 0xFFFFFFFFu; }
            __syncthreads();
            for (int i = tid; i < nd; i += NT) {
                uint k = key_of(sh[i]);
                uint b = k >> 11;
                if (b == pA) atomicMax(&selres[0], k);
                if (b == pB) atomicMin(&selres[1], k);
            }
            __syncthreads();
            va = selres[0]; vb = selres[1];
            __syncthreads();
        } else {
            uint pfx = (p1 << 10) | B1.x;
            if (tid < 1024) hist[tid] = 0u;
            __syncthreads();
            for (int i = tid; i < nd; i += NT) {
                uint k = key_of(sh[i]);
                if ((k >> 11) == pfx) atomicAdd(&hist[(k >> 1) & 1023u], 1u);
            }
            __syncthreads();
            uint2 C1 = hist_locate1k(hist, tid, r1 - A1.y - B1.y, wsum, selres);
            uint2 C2 = hist_locate1k(hist, tid, r2 - A1.y - B1.y, wsum, selres);
            va = ((pfx << 10) | C1.x) << 1;
            vb = ((pfx << 10) | C2.x) << 1;
        }
    }
    return 0.5f * (sqrtf(__uint_as_float(va)) + sqrtf(__uint_as_float(vb)));
}

// register-key median for the ROOT (8 keys/thread)
__device__ __forceinline__ float median_root_reg(
    const float2 (&v)[8], int tid, uint* hist, uint* wsum, uint* selres)
{
    const uint r1 = NN / 2 - 1, r2 = NN / 2;
    hist[tid] = 0u;
    __syncthreads();
    #pragma unroll
    for (int t = 0; t < 8; ++t) atomicAdd(&hist[key_of(v[t]) >> 21], 1u);
    __syncthreads();
    uint2 A1 = hist_locate1k(hist, tid, r1, wsum, selres);
    uint2 A2 = hist_locate1k(hist, tid, r2, wsum, selres);
    uint va, vb;
    if (A1.x != A2.x) {
        if (tid == 0) { selres[0] = 0u; selres[1] = 0xFFFFFFFFu; }
        __syncthreads();
        #pragma unroll
        for (int t = 0; t < 8; ++t) {
            uint k = key_of(v[t]);
            uint b = k >> 21;
            if (b == A1.x) atomicMax(&selres[0], k);
            if (b == A2.x) atomicMin(&selres[1], k);
        }
        __syncthreads();
        va = selres[0]; vb = selres[1];
        __syncthreads();
    } else {
        uint p1 = A1.x;
        hist[tid] = 0u;
        __syncthreads();
        #pragma unroll
        for (int t = 0; t < 8; ++t) {
            uint k = key_of(v[t]);
            if ((k >> 21) == p1) atomicAdd(&hist[(k >> 11) & 1023u], 1u);
        }
        __syncthreads();
        uint2 B1 = hist_locate1k(hist, tid, r1 - A1.y, wsum, selres);
        uint2 B2 = hist_locate1k(hist, tid, r2 - A1.y, wsum, selres);
        if (B1.x != B2.x) {
            uint pA = (p1 << 10) | B1.x, pB = (p1 << 10) | B2.x;
            if (tid == 0) { selres[0] = 0u; selres[1] = 0xFFFFFFFFu; }
            __syncthreads();
            #pragma unroll
            for (int t = 0; t < 8; ++t) {
                uint k = key_of(v[t]);
                uint b = k >> 11;
                if (b == pA) atomicMax(&selres[0], k);
                if (b == pB) atomicMin(&selres[1], k);
            }
            __syncthreads();
            va = selres[0]; vb = selres[1];
            __syncthreads();
        } else {
            uint pfx = (p1 << 10) | B1.x;
            hist[tid] = 0u;
            __syncthreads();
            #pragma unroll
            for (int t = 0; t < 8; ++t) {
                uint k = key_of(v[t]);
                if ((k >> 11) == pfx) atomicAdd(&hist[(k >> 1) & 1023u], 1u);
            }
            __syncthreads();
            uint2 C1 = hist_locate1k(hist, tid, r1 - A1.y - B1.y, wsum, selres);
            uint2 C2 = hist_locate1k(hist, tid, r2 - A1.y - B1.y, wsum, selres);
            va = ((pfx << 10) | C1.x) << 1;
            vb = ((pfx << 10) | C2.x) << 1;
        }
    }
    return 0.5f * (sqrtf(__uint_as_float(va)) + sqrtf(__uint_as_float(vb)));
}

// -------- per-node MLP constants + per-element apply --------
struct NodeConst {
    float hbd, gbase, hb[12], bo0, bo1;
};
__device__ __forceinline__ NodeConst node_consts(
    int D, int nodes, int n, int g, int ND, int row,
    const float* __restrict__ Wp, const float* __restrict__ bp,
    const float* __restrict__ Wo, const float* __restrict__ bo,
    const float* __restrict__ Se, const float* __restrict__ Coh,
    float lfg, float sigma, float hfg, float cutoff)
{
    NodeConst nc;
    float bcv = (D == 0) ? 0.f : ((float)n + 0.5f) / (float)nodes;
    float coh = Coh[g * ROWS + row];
    float sev = Se[g * ROWS + row];
    float nle = __logf(fmaxf(sev * (1.f / (float)ND), EPSF));
    float dnv = (float)D * 0.25f;
    float lbb = 1.f + lfg * __expf(-(bcv * bcv) / (sigma * sigma));
    nc.hbd = hfg + (1.f - hfg) * fast_rcp(1.f + __expf(-(cutoff - bcv) / sigma));
    nc.gbase = lbb * nc.hbd * (1.f + lfg * coh) * (hfg + (1.f - hfg) * coh);
    #pragma unroll
    for (int j = 0; j < 12; ++j)
        nc.hb[j] = bp[j] + nle * Wp[j*7+2] + dnv * Wp[j*7+3] + bcv * Wp[j*7+4] + coh * Wp[j*7+5];
    nc.bo0 = bo[0]; nc.bo1 = bo[1];
    return nc;
}

__device__ __forceinline__ float2 mlp_apply(
    float2 cv, int o, int D, float invnm1, const NodeConst& nc,
    const float* __restrict__ Wp, const float* __restrict__ Wo)
{
    float m2 = fmaf(cv.x, cv.x, cv.y * cv.y);
    float f0 = 0.5f * __logf(fmaxf(m2, 1e-12f));
    float f1 = fast_atan2f(cv.y, cv.x) * INV_PIF;
    int itrue = (int)(__brev((uint)o) >> (19 + D));
    float f6 = (float)itrue * invnm1;
    float acc0 = nc.bo0, acc1 = nc.bo1;
    #pragma unroll
    for (int j = 0; j < 12; ++j) {
        float h = fmaf(f0, Wp[j*7], fmaf(f1, Wp[j*7+1], fmaf(f6, Wp[j*7+6], nc.hb[j])));
        float s = silu_pade(h);
        acc0 = fmaf(s, Wo[j], acc0);
        acc1 = fmaf(s, Wo[12 + j], acc1);
    }
    float gm = nc.gbase * exp_small(0.25f * tanh_pade(acc0));
    float tp = tanh_pade(acc1);
    float spv = sin_halfpi(tp), cpv = cos_halfpi(tp);
    return make_float2(gm * (cv.x * cpv - cv.y * spv),
                       gm * (cv.x * spv + cv.y * cpv));
}

// -------- rare-path generic node filter (runtime D>=1, via sh window) ------
__device__ __forceinline__ void filter_generic(
    int D, int n, float2 (&v)[8], int tid, float2* sh,
    const float* __restrict__ Wp, const float* __restrict__ bp,
    const float* __restrict__ Wo, const float* __restrict__ bo,
    const float* __restrict__ Se, const float* __restrict__ Coh,
    const int* __restrict__ fPg, int row,
    uint* hist, uint* wsum, uint* selres,
    float lfg, float sigma, float hfg, float cutoff)
{
    int nd = NN >> D;
    int g = (1 << D) - 1 + n;
    // copy-in (static v indices)
    if (D <= 3) {
        int CNT = 8 >> D;
        #pragma unroll
        for (int t = 0; t < 8; ++t) {
            int k = t - n * CNT;
            if ((unsigned)k < (unsigned)CNT) sh[tid + (k << 10)] = v[t];
        }
    } else {
        bool own = ((tid >> 9) == (n & 1));
        #pragma unroll
        for (int t = 0; t < 8; ++t)
            if (t == (n >> 1) && own) sh[tid & 511] = v[t];
    }
    __syncthreads();

    NodeConst nc = node_consts(D, 1 << D, n, g, nd, row, Wp, bp, Wo, bo, Se, Coh,
                               lfg, sigma, hfg, cutoff);
    float invnm1 = 1.f / (float)(nd - 1);
    for (int i = tid; i < nd; i += NT)
        sh[i] = mlp_apply(sh[i], i, D, invnm1, nc, Wp, Wo);
    __syncthreads();

    float nf = median_dyn(sh, nd, tid, hist, wsum, selres);
    float thr = (1.f - nc.hbd) * nf;
    float pf = fPg[g] ? (hfg * hfg) : 1.f;
    for (int i = tid; i < nd; i += NT) {
        float2 w = sh[i];
        float fm = sqrtf(fmaf(w.x, w.x, w.y * w.y));
        float den = fmaxf(fm - thr, 0.f);
        float s = den * fast_rcp(fmaxf(fm, EPSF)) * pf;
        sh[i] = make_float2(w.x * s, w.y * s);
    }
    __syncthreads();
    // copy-out
    if (D <= 3) {
        int CNT = 8 >> D;
        #pragma unroll
        for (int t = 0; t < 8; ++t) {
            int k = t - n * CNT;
            if ((unsigned)k < (unsigned)CNT) v[t] = sh[tid + (k << 10)];
        }
    } else {
        bool own = ((tid >> 9) == (n & 1));
        #pragma unroll
        for (int t = 0; t < 8; ++t)
            if (t == (n >> 1) && own) v[t] = sh[tid & 511];
    }
    __syncthreads();
}

// -------- ROOT filter fully in registers (hot path) ------------------------
__device__ __forceinline__ void filter_root_reg(
    float2 (&v)[8], int tid,
    const float* __restrict__ Wp, const float* __restrict__ bp,
    const float* __restrict__ Wo, const float* __restrict__ bo,
    const float* __restrict__ Se, const float* __restrict__ Coh,
    const int* __restrict__ fPg, int row,
    uint* hist, uint* wsum, uint* selres,
    float lfg, float sigma, float hfg, float cutoff)
{
    NodeConst nc = node_consts(0, 1, 0, 0, NN, row, Wp, bp, Wo, bo, Se, Coh,
                               lfg, sigma, hfg, cutoff);
    float invnm1 = 1.f / (float)(NN - 1);
    #pragma unroll
    for (int t = 0; t < 8; ++t) {
        int o = tid + (t << 10);
        v[t] = mlp_apply(v[t], o, 0, invnm1, nc, Wp, Wo);
    }
    float nf = median_root_reg(v, tid, hist, wsum, selres);
    float thr = (1.f - nc.hbd) * nf;
    float pf = fPg[0] ? (hfg * hfg) : 1.f;
    #pragma unroll
    for (int t = 0; t < 8; ++t) {
        float2 w = v[t];
        float fm = sqrtf(fmaf(w.x, w.x, w.y * w.y));
        float den = fmaxf(fm - thr, 0.f);
        float s = den * fast_rcp(fmaxf(fm, EPSF)) * pf;
        v[t] = make_float2(w.x * s, w.y * s);
    }
}

// register Haar merge, slot stride DT
template<int DT>
__device__ __forceinline__ void merge_reg(float2 (&v)[8]){
    #pragma unroll
    for (int t = 0; t < 8; ++t) {
        if ((t & DT) == 0) {
            float2 lo = v[t], hi = v[t + DT];
            v[t]      = make_float2((lo.x + hi.x) * SQRT1_2F, (lo.y + hi.y) * SQRT1_2F);
            v[t + DT] = make_float2((lo.x - hi.x) * SQRT1_2F, (lo.y - hi.y) * SQRT1_2F);
        }
    }
}

// ======================= K3: apply + inverse FFT ===========================
__global__ __launch_bounds__(NT, 8) void k_rest(
    const uint* __restrict__ Lv16,
    const float* __restrict__ Se, const float* __restrict__ Coh,
    const int* __restrict__ fFg, const int* __restrict__ fPg,
    float* __restrict__ out,
    const float* __restrict__ Wp, const float* __restrict__ bp,
    const float* __restrict__ Wo, const float* __restrict__ bo,
    const float* lfg_p, const float* sig_p, const float* hfg_p, const float* cut_p)
{
    __shared__ float2 sh[NN];                   // 64KB
    __shared__ __align__(16) uint hist[1024];   // 4KB
    __shared__ uint wsum[16];
    __shared__ uint selres[2];

    int row = blockIdx.x, tid = threadIdx.x;
    float lfg = *lfg_p, sigma = *sig_p, hfg = *hfg_p, cutoff = *cut_p;

    const uint* lr = Lv16 + ((size_t)row << LOGN);
    float2 v[8];
    #pragma unroll
    for (int t = 0; t < 8; ++t) v[t] = unpack_h2(lr[tid + (t << 10)]);

    // d4 leaf filters (rare)
    for (int n = 0; n < 16; ++n)
        if (fFg[15 + n])
            filter_generic(4, n, v, tid, sh, Wp, bp, Wo, bo, Se, Coh, fPg, row, hist, wsum, selres, lfg, sigma, hfg, cutoff);

    // d3 merge: stride 512 (cross-thread) via LDS
    #pragma unroll
    for (int t = 0; t < 8; ++t) sh[tid + (t << 10)] = v[t];
    __syncthreads();
    #pragma unroll
    for (int t = 0; t < 4; ++t) {
        int q = tid + (t << 10);
        int p = ((q >> 9) << 10) | (q & 511);
        float2 a = sh[p], b = sh[p + 512];
        sh[p]       = make_float2((a.x + b.x) * SQRT1_2F, (a.y + b.y) * SQRT1_2F);
        sh[p + 512] = make_float2((a.x - b.x) * SQRT1_2F, (a.y - b.y) * SQRT1_2F);
    }
    __syncthreads();
    #pragma unroll
    for (int t = 0; t < 8; ++t) v[t] = sh[tid + (t << 10)];
    __syncthreads();

    for (int n = 0; n < 8; ++n)
        if (fFg[7 + n])
            filter_generic(3, n, v, tid, sh, Wp, bp, Wo, bo, Se, Coh, fPg, row, hist, wsum, selres, lfg, sigma, hfg, cutoff);
    merge_reg<1>(v);
    for (int n = 0; n < 4; ++n)
        if (fFg[3 + n])
            filter_generic(2, n, v, tid, sh, Wp, bp, Wo, bo, Se, Coh, fPg, row, hist, wsum, selres, lfg, sigma, hfg, cutoff);
    merge_reg<2>(v);
    for (int n = 0; n < 2; ++n)
        if (fFg[1 + n])
            filter_generic(1, n, v, tid, sh, Wp, bp, Wo, bo, Se, Coh, fPg, row, hist, wsum, selres, lfg, sigma, hfg, cutoff);
    merge_reg<4>(v);
    if (fFg[0])
        filter_root_reg(v, tid, Wp, bp, Wo, bo, Se, Coh, fPg, row, hist, wsum, selres, lfg, sigma, hfg, cutoff);

    // ---- inverse FFT: 5 LDS radix-4 stages, then 3 register DIT levels ----
    #pragma unroll
    for (int t = 0; t < 8; ++t) sh[tid + (t << 10)] = v[t];
    __syncthreads();
    inv_r4_stage<1, 0>(sh, tid);     // 1,2
    inv_r4_stage<4, 2>(sh, tid);     // 4,8
    inv_r4_stage<16, 4>(sh, tid);    // 16,32
    inv_r4_stage<64, 6>(sh, tid);    // 64,128
    inv_r4_stage<256, 8>(sh, tid);   // 256,512
    #pragma unroll
    for (int t = 0; t < 8; ++t) v[t] = sh[tid + (t << 10)];
    {
        float a0 = PIF * (1.0f / 4096.0f) * (float)tid;
        float2 w1 = make_float2(__cosf(a0), __sinf(a0));
        float2 w2 = cmul(w1, w1);
        float2 w4 = cmul(w2, w2);
        #pragma unroll
        for (int t = 0; t < 8; ++t) if (!(t & 1)) {        // h=1024
            float2 tb = cmul(w4, v[t + 1]);
            float2 a = v[t];
            v[t] = cadd(a, tb);
            v[t + 1] = csub(a, tb);
        }
        #pragma unroll
        for (int t = 0; t < 8; ++t) if (!(t & 2)) {        // h=2048
            float2 W = (t & 1) ? make_float2(-w2.y, w2.x) : w2;
            float2 tb = cmul(W, v[t + 2]);
            float2 a = v[t];
            v[t] = cadd(a, tb);
            v[t + 2] = csub(a, tb);
        }
        const float2 K4p[4] = {{1.f,0.f},{C4C,C4C},{0.f,1.f},{-C4C,C4C}};
        #pragma unroll
        for (int t = 0; t < 4; ++t) {                      // h=4096
            float2 W = cmul(w1, K4p[t]);
            float2 tb = cmul(W, v[t + 4]);
            float2 a = v[t];
            v[t] = cadd(a, tb);
            v[t + 4] = csub(a, tb);
        }
    }
    float* orow = out + ((size_t)row << LOGN);
    #pragma unroll
    for (int t = 0; t < 8; ++t)
        orow[tid + (t << 10)] = v[t].x * (1.0f / (float)NN);
}

// ---------------- host launch ----------------------------------------------
extern "C" void kernel_launch(void* const* d_in, const int* in_sizes, int n_in,
                              void* d_out, int out_size, void* d_ws, size_t ws_size,
                              hipStream_t stream) {
    const float* x   = (const float*)d_in[0];
    const float* Wp  = (const float*)d_in[1];
    const float* bp  = (const float*)d_in[2];
    const float* Wo  = (const float*)d_in[3];
    const float* bo  = (const float*)d_in[4];
    const float* lfg = (const float*)d_in[5];
    const float* sig = (const float*)d_in[6];
    const float* hfg = (const float*)d_in[7];
    const float* cut = (const float*)d_in[8];
    float* out = (float*)d_out;

    size_t LVB = (size_t)ROWS * NN * sizeof(uint);   // 16,777,216 B (fp16x2 leaves)
    char* ws = (char*)d_ws;
    uint*   Lv16 = (uint*)ws;
    float*  Se   = (float*)(ws + LVB);
    float*  Coh  = Se  + (size_t)NNODES * ROWS;
    float*  Ent  = Coh + (size_t)NNODES * ROWS;
    int*    fFg  = (int*)(Ent + (size_t)NNODES * ROWS);
    int*    fPg  = fFg + NNODES;
    size_t need = (size_t)((char*)(fPg + NNODES) - ws);
    if (ws_size < need) return;

    k_pre   <<<dim3(ROWS), dim3(NT),  0, stream>>>(x, Lv16, Se, Coh, Ent, lfg, sig, hfg, cut);
    k_decide<<<dim3(1),    dim3(512), 0, stream>>>(Se, Coh, Ent, fFg, fPg);
    k_rest  <<<dim3(ROWS), dim3(NT),  0, stream>>>(Lv16, Se, Coh, fFg, fPg, out, Wp, bp, Wo, bo, lfg, sig, hfg, cut);
}

// Round 12
// 125.615 us; speedup vs baseline: 1.3907x; 1.3907x over previous
//
#include <hip/hip_runtime.h>
#include <hip/hip_fp16.h>
#include <math.h>

#define NN      8192
#define LOGN    13
#define ROWS    512
#define NT      512
#define NNODES  31
#define EPSF    1e-6f
#define PRUNEF  0.05f
#define SQRT1_2F 0.70710678118654752f
#define PIF      3.14159265358979323f
#define INV_PIF  0.31830988618379067f

typedef unsigned int uint;

// ---------------- fast math ----------------
__device__ __forceinline__ float fast_rcp(float x){ return __builtin_amdgcn_rcpf(x); }
__device__ __forceinline__ float fast_rsq(float x){ return __builtin_amdgcn_rsqf(x); }

__device__ __forceinline__ float tanh_pade(float y){
    y = fminf(3.f, fmaxf(-3.f, y));
    float y2 = y * y;
    float num = y * fmaf(y2, 10.f, 105.f);
    float den = fmaf(y2, 45.f, fmaf(y2 * y2, 1.f, 105.f));
    return num * fast_rcp(den);
}
__device__ __forceinline__ float silu_pade(float h){
    float y = fminf(3.f, fmaxf(-3.f, 0.5f * h));
    float y2 = y * y;
    float num = y * fmaf(y2, 10.f, 105.f);
    float den = fmaf(y2, 45.f, fmaf(y2 * y2, 1.f, 105.f));
    return 0.5f * h * (1.f + num * fast_rcp(den));
}
__device__ __forceinline__ float exp_small(float z){
    return fmaf(z, fmaf(z, fmaf(z, fmaf(z, 0.041666667f, 0.16666667f), 0.5f), 1.f), 1.f);
}
__device__ __forceinline__ float sin_halfpi(float t){
    float t2 = t * t;
    return t * fmaf(t2, fmaf(t2, fmaf(t2, -4.6817541e-3f, 7.96926262e-2f), -6.45964097e-1f), 1.57079632f);
}
__device__ __forceinline__ float cos_halfpi(float t){
    float t2 = t * t;
    return fmaf(t2, fmaf(t2, fmaf(t2, fmaf(t2, 9.1937e-4f, -2.08634807e-2f), 2.53669508e-1f), -1.23370055f), 1.f);
}

__device__ __forceinline__ float fast_atan2f(float y, float x) {
    float ay = fabsf(y), ax = fabsf(x);
    float mx = fmaxf(ax, ay), mn = fminf(ax, ay);
    float a = (mx > 0.f) ? (mn * fast_rcp(mx)) : 0.f;
    bool big = a > 0.4142135679f;
    float t = big ? ((a - 1.f) * fast_rcp(a + 1.f)) : a;
    float z2 = t * t;
    float p = fmaf(8.05374449538e-2f, z2, -1.38776856032e-1f);
    p = fmaf(p, z2, 1.99777106478e-1f);
    p = fmaf(p, z2, -3.33329491539e-1f);
    float r = fmaf(p * z2, t, t);
    if (big) r += 0.78539816339744831f;
    if (ay > ax) r = 1.57079632679489662f - r;
    if (x < 0.f) r = 3.14159265358979323f - r;
    return copysignf(r, y);
}

__device__ __forceinline__ float2 cmul(float2 a, float2 b){
    return make_float2(a.x*b.x - a.y*b.y, a.x*b.y + a.y*b.x);
}
__device__ __forceinline__ float2 cadd(float2 a, float2 b){ return make_float2(a.x+b.x, a.y+b.y); }
__device__ __forceinline__ float2 csub(float2 a, float2 b){ return make_float2(a.x-b.x, a.y-b.y); }

__device__ __forceinline__ uint pack_h2(float2 v){
    __half2 h = __floats2half2_rn(v.x, v.y);
    return __builtin_bit_cast(uint, h);
}
__device__ __forceinline__ float2 unpack_h2(uint u){
    __half2 h = __builtin_bit_cast(__half2, u);
    return make_float2(__low2float(h), __high2float(h));
}

__device__ __forceinline__ void wave_red8(float* a) {
    #pragma unroll
    for (int m = 32; m >= 1; m >>= 1) {
        #pragma unroll
        for (int q = 0; q < 8; ++q) a[q] += __shfl_xor(a[q], m);
    }
}

#define C8C 0.92387953251f
#define S8C 0.38268343236f
#define C4C 0.70710678119f

// ---- forward LDS radix-4 stage on a 4096-elem batch window ----
// 1024 butterflies -> 2 chunks of 512. HH <= 128 so twiddle hoists.
template<int HH, int LG>
__device__ __forceinline__ void fwd_r4_batch(float2* shw, int tid) {
    int j = tid & (HH - 1);
    float ang = (-PIF / (2.0f * (float)HH)) * (float)j;
    float s = __sinf(ang), co = __cosf(ang);
    float2 t1 = make_float2(co, s);
    float2 t2 = make_float2(co * co - s * s, 2.f * co * s);
    #pragma unroll
    for (int c = 0; c < 2; ++c) {
        int q = tid + (c << 9);
        int p = ((q >> LG) << (LG + 2)) | j;
        float2 a = shw[p], b = shw[p + HH], cc = shw[p + 2*HH], d = shw[p + 3*HH];
        float2 a1 = cadd(a, cc);
        float2 c1 = cmul(csub(a, cc), t1);
        float2 b1 = cadd(b, d);
        float2 u  = cmul(csub(b, d), t1);
        float2 d1 = make_float2(u.y, -u.x);          // -i*u
        shw[p]        = cadd(a1, b1);
        shw[p + HH]   = cmul(csub(a1, b1), t2);
        shw[p + 2*HH] = cadd(c1, d1);
        shw[p + 3*HH] = cmul(csub(c1, d1), t2);
    }
    __syncthreads();
}

// ---- inverse LDS radix-4 stage on a 4096-elem batch window ----
template<int H, int LG>
__device__ __forceinline__ void inv_r4_batch(float2* shw, int tid) {
    int jj = tid & (H - 1);
    float ang = (PIF / (2.0f * (float)H)) * (float)jj;
    float s2 = __sinf(ang), c2 = __cosf(ang);
    float2 t2 = make_float2(c2, s2);
    float2 t1 = make_float2(c2 * c2 - s2 * s2, 2.f * c2 * s2);
    #pragma unroll
    for (int c = 0; c < 2; ++c) {
        int q = tid + (c << 9);
        int p0 = ((q >> LG) << (LG + 2)) | jj;
        float2 a = shw[p0], b = shw[p0 + H], cc = shw[p0 + 2*H], d = shw[p0 + 3*H];
        float2 tb = cmul(t1, b);
        float2 ap = cadd(a, tb), bp2 = csub(a, tb);
        float2 td = cmul(t1, d);
        float2 cp = cadd(cc, td), dp2 = csub(cc, td);
        float2 tc = cmul(t2, cp);
        float2 u  = cmul(t2, dp2);
        float2 iB = make_float2(-u.y, u.x);          // +i*u
        shw[p0]       = cadd(ap, tc);
        shw[p0 + H]   = cadd(bp2, iB);
        shw[p0 + 2*H] = csub(ap, tc);
        shw[p0 + 3*H] = csub(bp2, iB);
    }
    __syncthreads();
}

// ======================= K1: FFT + filter + stats pyramid ==================
__global__ __launch_bounds__(NT, 4) void k_pre(
    const float* __restrict__ x, uint* __restrict__ Lv16,
    float* __restrict__ Se, float* __restrict__ Coh, float* __restrict__ Ent,
    const float* lfg_p, const float* sig_p, const float* hfg_p, const float* cut_p)
{
    __shared__ float2 shw[4096];     // 32KB batch window
    __shared__ float4 wred[8];
    __shared__ float nacc[30 * 4];
    int row = blockIdx.x, tid = threadIdx.x;
    float lfg = *lfg_p, sigma = *sig_p, hfg = *hfg_p, cutoff = *cut_p;

    // ---- load natural-order comb straight into registers ----
    const float* xr = x + ((size_t)row << LOGN);
    float2 v[16];
    #pragma unroll
    for (int t = 0; t < 16; ++t)
        v[t] = make_float2(xr[tid + (t << 9)], 0.f);

    // ---- phase A: 4 register DIF levels (halves 4096,2048,1024,512) ----
    {
        float a0 = -PIF * (1.0f / 4096.0f) * (float)tid;
        float2 w1 = make_float2(__cosf(a0), __sinf(a0));
        float2 w2 = cmul(w1, w1);
        float2 w4 = cmul(w2, w2);
        float2 w8 = cmul(w4, w4);
        const float2 K16[8] = {
            { 1.f, 0.f}, { C8C, -S8C}, { C4C, -C4C}, { S8C, -C8C},
            { 0.f,-1.f}, {-S8C, -C8C}, {-C4C, -C4C}, {-C8C, -S8C}};
        #pragma unroll
        for (int t = 0; t < 8; ++t) {
            float2 W = cmul(w1, K16[t]);
            float2 a = v[t], b = v[t + 8];
            v[t] = cadd(a, b);
            v[t + 8] = cmul(csub(a, b), W);
        }
        const float2 K8a[4] = {{1.f,0.f},{C4C,-C4C},{0.f,-1.f},{-C4C,-C4C}};
        #pragma unroll
        for (int t = 0; t < 16; ++t) if (!(t & 4)) {
            float2 W = cmul(w2, K8a[t & 3]);
            float2 a = v[t], b = v[t + 4];
            v[t] = cadd(a, b);
            v[t + 4] = cmul(csub(a, b), W);
        }
        #pragma unroll
        for (int t = 0; t < 16; ++t) if (!(t & 2)) {
            float2 W = (t & 1) ? make_float2(w4.y, -w4.x) : w4;   // w4 * (0,-1)
            float2 a = v[t], b = v[t + 2];
            v[t] = cadd(a, b);
            v[t + 2] = cmul(csub(a, b), W);
        }
        #pragma unroll
        for (int t = 0; t < 16; ++t) if (!(t & 1)) {
            float2 a = v[t], b = v[t + 1];
            v[t] = cadd(a, b);
            v[t + 1] = cmul(csub(a, b), w8);
        }
    }

    if (tid < 120) nacc[tid] = 0.f;      // zero pyramid accumulators

    // ---- phase B: 9 LDS levels, 2 batches of 8 runs through 32KB window ----
    #pragma unroll
    for (int b = 0; b < 2; ++b) {
        __syncthreads();                 // window free (covers nacc zero too)
        #pragma unroll
        for (int k = 0; k < 8; ++k) shw[tid + (k << 9)] = v[8 * b + k];
        __syncthreads();
        fwd_r4_batch<128, 7>(shw, tid);  // levels 256,128
        fwd_r4_batch<32, 5>(shw, tid);   // levels 64,32
        fwd_r4_batch<8, 3>(shw, tid);    // levels 16,8
        fwd_r4_batch<2, 1>(shw, tid);    // levels 4,2
        #pragma unroll
        for (int c = 0; c < 4; ++c) {    // level 1 (no twiddle), 2048 pairs
            int p = (tid + (c << 9)) << 1;
            float2 a = shw[p], bb = shw[p + 1];
            shw[p] = cadd(a, bb);
            shw[p + 1] = csub(a, bb);
        }
        __syncthreads();
        #pragma unroll
        for (int k = 0; k < 8; ++k) v[8 * b + k] = shw[tid + (k << 9)];
    }

    // ---- frequency filter + root stats (registers) ----
    float inv_gs = 1.f / fmaxf(sigma, 0.05f);
    float is2 = 1.f / (sigma * sigma);
    float se = 0.f, slg = 0.f, sux = 0.f, suy = 0.f;
    #pragma unroll
    for (int t = 0; t < 16; ++t) {
        int p = tid + (t << 9);
        int k = (int)(__brev((uint)p) >> 19);            // true frequency index
        float fk = (k < NN / 2) ? (float)k : (float)(k - NN);
        float f = fk * (1.0f / (float)NN);
        float r2 = f * f;
        float lfb = 1.f + lfg * __expf(-r2 * is2);
        float radius = sqrtf(r2 + 1e-12f);
        float gate = fast_rcp(1.f + __expf(-(cutoff - radius) * inv_gs));
        float mult = lfb * (hfg + (1.f - hfg) * gate);
        float2 c = v[t];
        c.x *= mult; c.y *= mult;
        v[t] = c;
        float e = fmaf(c.x, c.x, c.y * c.y);
        se += e;
        slg += e * __logf(fmaxf(e, 1e-30f));
        float inv = fminf(fast_rsq(e), 1e6f);
        sux += c.x * inv; suy += c.y * inv;
    }
    #pragma unroll
    for (int m = 32; m >= 1; m >>= 1) {
        se += __shfl_xor(se, m); slg += __shfl_xor(slg, m);
        sux += __shfl_xor(sux, m); suy += __shfl_xor(suy, m);
    }
    if ((tid & 63) == 0) wred[tid >> 6] = make_float4(se, slg, sux, suy);
    __syncthreads();
    if (tid == 0) {
        float4 r = wred[0];
        #pragma unroll
        for (int w = 1; w < 8; ++w) {
            r.x += wred[w].x; r.y += wred[w].y; r.z += wred[w].z; r.w += wred[w].w;
        }
        float gx = r.z / (float)NN, gy = r.w / (float)NN;
        float ga = sqrtf(gx * gx + gy * gy);
        float denom = fmaxf(r.x, EPSF);
        Se[row]  = r.x;
        Ent[row] = __logf(denom) - r.y / denom;
        Coh[row] = fminf(ga, 1.f);
    }

    // ---- pyramid: 4 register split levels with fused child stats ----
    #pragma unroll
    for (int DP = 0; DP < 4; ++DP) {
        int ST = 8 >> DP;
        #pragma unroll
        for (int t = 0; t < 16; ++t) {
            if ((t & ST) == 0) {
                float2 a = v[t], b = v[t + ST];
                v[t]      = make_float2((a.x + b.x) * SQRT1_2F, (a.y + b.y) * SQRT1_2F);
                v[t + ST] = make_float2((a.x - b.x) * SQRT1_2F, (a.y - b.y) * SQRT1_2F);
            }
        }
        int CNT = 16 >> (DP + 1);
        int NPAIR = 1 << DP;
        int G0 = (2 << DP) - 1;
        #pragma unroll
        for (int pr = 0; pr < NPAIR; ++pr) {
            float acc[8] = {0,0,0,0,0,0,0,0};
            #pragma unroll
            for (int s = 0; s < 16; ++s) {
                int k0 = s - (2 * pr) * CNT;
                if (k0 >= 0 && k0 < CNT) {
                    float2 w = v[s];
                    float e = fmaf(w.x, w.x, w.y * w.y);
                    acc[0] += e; acc[1] += e * __logf(fmaxf(e, 1e-30f));
                    float iv = fminf(fast_rsq(e), 1e6f);
                    acc[2] += w.x * iv; acc[3] += w.y * iv;
                }
                int k1 = s - (2 * pr + 1) * CNT;
                if (k1 >= 0 && k1 < CNT) {
                    float2 w = v[s];
                    float e = fmaf(w.x, w.x, w.y * w.y);
                    acc[4] += e; acc[5] += e * __logf(fmaxf(e, 1e-30f));
                    float iv = fminf(fast_rsq(e), 1e6f);
                    acc[6] += w.x * iv; acc[7] += w.y * iv;
                }
            }
            wave_red8(acc);
            if ((tid & 63) == 0) {
                int ga = G0 + 2 * pr, gb = ga + 1;
                atomicAdd(&nacc[(ga-1)*4+0], acc[0]); atomicAdd(&nacc[(ga-1)*4+1], acc[1]);
                atomicAdd(&nacc[(ga-1)*4+2], acc[2]); atomicAdd(&nacc[(ga-1)*4+3], acc[3]);
                atomicAdd(&nacc[(gb-1)*4+0], acc[4]); atomicAdd(&nacc[(gb-1)*4+1], acc[5]);
                atomicAdd(&nacc[(gb-1)*4+2], acc[6]); atomicAdd(&nacc[(gb-1)*4+3], acc[7]);
            }
        }
    }
    __syncthreads();
    if (tid < 30) {
        int g = tid + 1;
        float E = nacc[tid * 4 + 0], SL = nacc[tid * 4 + 1];
        float ZX = nacc[tid * 4 + 2], ZY = nacc[tid * 4 + 3];
        float denom = fmaxf(E, EPSF);
        float ent = __logf(denom) - SL / denom;
        int d = 31 - __clz(g + 1);
        float invn = 1.f / (float)(NN >> d);
        float zx = ZX * invn, zy = ZY * invn;
        float ch = fminf(sqrtf(zx * zx + zy * zy), 1.f);
        Se[g * ROWS + row] = E; Coh[g * ROWS + row] = ch; Ent[g * ROWS + row] = ent;
    }

    // ---- store depth-4 leaves packed fp16 from regs ----
    uint* lrow = Lv16 + ((size_t)row << LOGN);
    #pragma unroll
    for (int t = 0; t < 16; ++t)
        lrow[tid + (t << 9)] = pack_h2(v[t]);
}

// ======================= K2: decide (1 block) ==============================
__global__ __launch_bounds__(NT) void k_decide(
    const float* __restrict__ Se, const float* __restrict__ Coh, const float* __restrict__ Ent,
    int* __restrict__ fFg, int* __restrict__ fPg)
{
    __shared__ float dtmp[3 * NNODES];
    __shared__ int fF[NNODES], fP[NNODES];
    int tid = threadIdx.x;
    float* dcost = dtmp; float* dne = dtmp + NNODES; float* dcm = dtmp + 2 * NNODES;
    int wid = tid >> 6, lane = tid & 63;
    for (int gn = wid; gn < NNODES; gn += 8) {
        float a = 0.f, b = 0.f, cc = 0.f;
        #pragma unroll
        for (int rr = 0; rr < ROWS / 64; ++rr) {
            int r = lane + (rr << 6);
            float ch = Coh[gn * ROWS + r];
            a += Ent[gn * ROWS + r] + 1.f - ch;
            b += Se[gn * ROWS + r];
            cc += ch;
        }
        #pragma unroll
        for (int m = 32; m >= 1; m >>= 1) {
            a += __shfl_xor(a, m); b += __shfl_xor(b, m); cc += __shfl_xor(cc, m);
        }
        if (lane == 0) { dcost[gn] = a / (float)ROWS; dne[gn] = b; dcm[gn] = cc / (float)ROWS; }
    }
    __syncthreads();
    if (tid == 0) {
        float mc[NNODES]; int sel[NNODES]; int act[NNODES];
        for (int gn = NNODES - 1; gn >= 0; --gn) {
            if (gn >= 15) { mc[gn] = dcost[gn]; sel[gn] = 0; }
            else {
                float chc = mc[2 * gn + 1] + mc[2 * gn + 2];
                sel[gn] = (chc < dcost[gn]) ? 1 : 0;
                mc[gn] = fminf(chc, dcost[gn]);
            }
        }
        float total_e = dne[0];
        act[0] = 1;
        for (int gn = 1; gn < NNODES; ++gn) {
            int p = (gn - 1) >> 1;
            act[gn] = act[p] && sel[p];
        }
        for (int gn = 0; gn < NNODES; ++gn) {
            int isleaf = (gn >= 15);
            fF[gn] = (act[gn] && (isleaf || !sel[gn])) ? 1 : 0;
            fP[gn] = ((dne[gn] / total_e < PRUNEF) || (dcm[gn] < PRUNEF)) ? 1 : 0;
        }
    }
    __syncthreads();
    if (tid < NNODES) { fFg[tid] = fF[tid]; fPg[tid] = fP[tid]; }
}

// ======================= median select helpers =============================
__device__ __forceinline__ uint key_of(float2 v) {
    return __float_as_uint(fmaf(v.x, v.x, v.y * v.y));
}
__device__ __forceinline__ uint key_at(const float2* sh, int p) { return key_of(sh[p]); }

__device__ __forceinline__ uint2 hist_locate1024(
    const uint* hist, int tid, uint r, uint* wsum, uint* selres)
{
    uint l0 = hist[2 * tid], l1 = hist[2 * tid + 1];
    uint s = l0 + l1;
    uint sc = s;
    #pragma unroll
    for (int o = 1; o < 64; o <<= 1) {
        uint v = __shfl_up(sc, o);
        if ((tid & 63) >= o) sc += v;
    }
    int wid = tid >> 6;
    if ((tid & 63) == 63) wsum[wid] = sc;
    __syncthreads();
    uint wb = 0;
    #pragma unroll
    for (int w = 0; w < 8; ++w) if (w < wid) wb += wsum[w];
    uint c0 = wb + sc - s;
    if (r >= c0 && r < c0 + l0) { selres[0] = 2u * tid;      selres[1] = c0; }
    c0 += l0;
    if (r >= c0 && r < c0 + l1) { selres[0] = 2u * tid + 1u; selres[1] = c0; }
    __syncthreads();
    uint2 res = make_uint2(selres[0], selres[1]);
    __syncthreads();
    return res;
}

// LDS-data median (D>=1 window path)
template<int EPT>
__device__ __forceinline__ float median_node(
    const float2* sh, int nd, int tid,
    uint* hist, uint* wsum, uint* selres)
{
    uint r1 = (uint)(nd / 2 - 1), r2 = (uint)(nd / 2);
    for (int k = tid; k < 1024; k += NT) hist[k] = 0u;
    __syncthreads();
    #pragma unroll
    for (int c = 0; c < EPT; ++c)
        atomicAdd(&hist[key_at(sh, tid + (c << 9)) >> 21], 1u);
    __syncthreads();
    uint2 A1 = hist_locate1024(hist, tid, r1, wsum, selres);
    uint2 A2 = hist_locate1024(hist, tid, r2, wsum, selres);
    uint va, vb;
    if (A1.x != A2.x) {
        if (tid == 0) { selres[0] = 0u; selres[1] = 0xFFFFFFFFu; }
        __syncthreads();
        #pragma unroll
        for (int c = 0; c < EPT; ++c) {
            uint k = key_at(sh, tid + (c << 9));
            uint b = k >> 21;
            if (b == A1.x) atomicMax(&selres[0], k);
            if (b == A2.x) atomicMin(&selres[1], k);
        }
        __syncthreads();
        va = selres[0]; vb = selres[1];
        __syncthreads();
    } else {
        uint p1 = A1.x;
        for (int k = tid; k < 1024; k += NT) hist[k] = 0u;
        __syncthreads();
        #pragma unroll
        for (int c = 0; c < EPT; ++c) {
            uint k = key_at(sh, tid + (c << 9));
            if ((k >> 21) == p1) atomicAdd(&hist[(k >> 11) & 1023u], 1u);
        }
        __syncthreads();
        uint2 B1 = hist_locate1024(hist, tid, r1 - A1.y, wsum, selres);
        uint2 B2 = hist_locate1024(hist, tid, r2 - A1.y, wsum, selres);
        if (B1.x != B2.x) {
            uint pA = (p1 << 10) | B1.x, pB = (p1 << 10) | B2.x;
            if (tid == 0) { selres[0] = 0u; selres[1] = 0xFFFFFFFFu; }
            __syncthreads();
            #pragma unroll
            for (int c = 0; c < EPT; ++c) {
                uint k = key_at(sh, tid + (c << 9));
                uint b = k >> 11;
                if (b == pA) atomicMax(&selres[0], k);
                if (b == pB) atomicMin(&selres[1], k);
            }
            __syncthreads();
            va = selres[0]; vb = selres[1];
            __syncthreads();
        } else {
            uint pfx = (p1 << 10) | B1.x;
            for (int k = tid; k < 1024; k += NT) hist[k] = 0u;
            __syncthreads();
            #pragma unroll
            for (int c = 0; c < EPT; ++c) {
                uint k = key_at(sh, tid + (c << 9));
                if ((k >> 11) == pfx) atomicAdd(&hist[(k >> 1) & 1023u], 1u);
            }
            __syncthreads();
            uint2 C1 = hist_locate1024(hist, tid, r1 - A1.y - B1.y, wsum, selres);
            uint2 C2 = hist_locate1024(hist, tid, r2 - A1.y - B1.y, wsum, selres);
            va = ((pfx << 10) | C1.x) << 1;
            vb = ((pfx << 10) | C2.x) << 1;
        }
    }
    return 0.5f * (sqrtf(__uint_as_float(va)) + sqrtf(__uint_as_float(vb)));
}

__device__ __forceinline__ float median_root_reg(
    const float2 (&v)[16], int tid, uint* hist, uint* wsum, uint* selres)
{
    const uint r1 = NN / 2 - 1, r2 = NN / 2;
    for (int k = tid; k < 1024; k += NT) hist[k] = 0u;
    __syncthreads();
    #pragma unroll
    for (int t = 0; t < 16; ++t)
        atomicAdd(&hist[key_of(v[t]) >> 21], 1u);
    __syncthreads();
    uint2 A1 = hist_locate1024(hist, tid, r1, wsum, selres);
    uint2 A2 = hist_locate1024(hist, tid, r2, wsum, selres);
    uint va, vb;
    if (A1.x != A2.x) {
        if (tid == 0) { selres[0] = 0u; selres[1] = 0xFFFFFFFFu; }
        __syncthreads();
        #pragma unroll
        for (int t = 0; t < 16; ++t) {
            uint k = key_of(v[t]);
            uint b = k >> 21;
            if (b == A1.x) atomicMax(&selres[0], k);
            if (b == A2.x) atomicMin(&selres[1], k);
        }
        __syncthreads();
        va = selres[0]; vb = selres[1];
        __syncthreads();
    } else {
        uint p1 = A1.x;
        for (int k = tid; k < 1024; k += NT) hist[k] = 0u;
        __syncthreads();
        #pragma unroll
        for (int t = 0; t < 16; ++t) {
            uint k = key_of(v[t]);
            if ((k >> 21) == p1) atomicAdd(&hist[(k >> 11) & 1023u], 1u);
        }
        __syncthreads();
        uint2 B1 = hist_locate1024(hist, tid, r1 - A1.y, wsum, selres);
        uint2 B2 = hist_locate1024(hist, tid, r2 - A1.y, wsum, selres);
        if (B1.x != B2.x) {
            uint pA = (p1 << 10) | B1.x, pB = (p1 << 10) | B2.x;
            if (tid == 0) { selres[0] = 0u; selres[1] = 0xFFFFFFFFu; }
            __syncthreads();
            #pragma unroll
            for (int t = 0; t < 16; ++t) {
                uint k = key_of(v[t]);
                uint b = k >> 11;
                if (b == pA) atomicMax(&selres[0], k);
                if (b == pB) atomicMin(&selres[1], k);
            }
            __syncthreads();
            va = selres[0]; vb = selres[1];
            __syncthreads();
        } else {
            uint pfx = (p1 << 10) | B1.x;
            for (int k = tid; k < 1024; k += NT) hist[k] = 0u;
            __syncthreads();
            #pragma unroll
            for (int t = 0; t < 16; ++t) {
                uint k = key_of(v[t]);
                if ((k >> 11) == pfx) atomicAdd(&hist[(k >> 1) & 1023u], 1u);
            }
            __syncthreads();
            uint2 C1 = hist_locate1024(hist, tid, r1 - A1.y - B1.y, wsum, selres);
            uint2 C2 = hist_locate1024(hist, tid, r2 - A1.y - B1.y, wsum, selres);
            va = ((pfx << 10) | C1.x) << 1;
            vb = ((pfx << 10) | C2.x) << 1;
        }
    }
    return 0.5f * (sqrtf(__uint_as_float(va)) + sqrtf(__uint_as_float(vb)));
}

// -------- shared per-node MLP constants --------
struct NodeConst {
    float hbd, gbase, hb[12], bo0, bo1;
};
__device__ __forceinline__ NodeConst node_consts(
    int D, int nodes, int n, int g, int ND, int row,
    const float* __restrict__ Wp, const float* __restrict__ bp,
    const float* __restrict__ Wo, const float* __restrict__ bo,
    const float* __restrict__ Se, const float* __restrict__ Coh,
    float lfg, float sigma, float hfg, float cutoff)
{
    NodeConst nc;
    float bcv = (D == 0) ? 0.f : ((float)n + 0.5f) / (float)nodes;
    float coh = Coh[g * ROWS + row];
    float sev = Se[g * ROWS + row];
    float nle = __logf(fmaxf(sev * (1.f / (float)ND), EPSF));
    float dnv = (float)D * 0.25f;
    float lbb = 1.f + lfg * __expf(-(bcv * bcv) / (sigma * sigma));
    nc.hbd = hfg + (1.f - hfg) * fast_rcp(1.f + __expf(-(cutoff - bcv) / sigma));
    nc.gbase = lbb * nc.hbd * (1.f + lfg * coh) * (hfg + (1.f - hfg) * coh);
    #pragma unroll
    for (int j = 0; j < 12; ++j)
        nc.hb[j] = bp[j] + nle * Wp[j*7+2] + dnv * Wp[j*7+3] + bcv * Wp[j*7+4] + coh * Wp[j*7+5];
    nc.bo0 = bo[0]; nc.bo1 = bo[1];
    return nc;
}

__device__ __forceinline__ float2 mlp_apply(
    float2 cv, int o, int D, float invnm1, const NodeConst& nc,
    const float* __restrict__ Wp, const float* __restrict__ Wo)
{
    float m2 = fmaf(cv.x, cv.x, cv.y * cv.y);
    float f0 = 0.5f * __logf(fmaxf(m2, 1e-12f));
    float f1 = fast_atan2f(cv.y, cv.x) * INV_PIF;
    int itrue = (int)(__brev((uint)o) >> (19 + D));
    float f6 = (float)itrue * invnm1;
    float acc0 = nc.bo0, acc1 = nc.bo1;
    #pragma unroll
    for (int j = 0; j < 12; ++j) {
        float h = fmaf(f0, Wp[j*7], fmaf(f1, Wp[j*7+1], fmaf(f6, Wp[j*7+6], nc.hb[j])));
        float s = silu_pade(h);
        acc0 = fmaf(s, Wo[j], acc0);
        acc1 = fmaf(s, Wo[12 + j], acc1);
    }
    float gm = nc.gbase * exp_small(0.25f * tanh_pade(acc0));
    float tp = tanh_pade(acc1);
    float spv = sin_halfpi(tp), cpv = cos_halfpi(tp);
    return make_float2(gm * (cv.x * cpv - cv.y * spv),
                       gm * (cv.x * spv + cv.y * cpv));
}

// -------- frontier node filter via LDS window (D>=1, rare path) ------------
template<int D>
__device__ __forceinline__ void filter_node_sh(
    float2 (&v)[16], int n, int tid, float2* shw,
    const float* __restrict__ Wp, const float* __restrict__ bp,
    const float* __restrict__ Wo, const float* __restrict__ bo,
    const float* __restrict__ Se, const float* __restrict__ Coh,
    const int* __restrict__ fPg, int row,
    uint* hist, uint* wsum, uint* selres,
    float lfg, float sigma, float hfg, float cutoff)
{
    constexpr int CNT = 16 >> D;          // <= 8 slots -> <= 4096 elems: fits window
    constexpr int ND  = NN >> D;
    constexpr int EPT = ND >> 9;
    int g = (1 << D) - 1 + n;

    #pragma unroll
    for (int t = 0; t < 16; ++t) {
        int k = t - n * CNT;
        if ((unsigned)k < (unsigned)CNT) shw[tid + (k << 9)] = v[t];
    }
    __syncthreads();

    NodeConst nc = node_consts(D, 1 << D, n, g, ND, row, Wp, bp, Wo, bo, Se, Coh,
                               lfg, sigma, hfg, cutoff);
    float invnm1 = 1.f / (float)(ND - 1);

    #pragma unroll
    for (int c = 0; c < EPT; ++c) {
        int o = tid + (c << 9);
        shw[o] = mlp_apply(shw[o], o, D, invnm1, nc, Wp, Wo);
    }
    __syncthreads();

    float nf = median_node<EPT>(shw, ND, tid, hist, wsum, selres);
    float thr = (1.f - nc.hbd) * nf;
    float pf = fPg[g] ? (hfg * hfg) : 1.f;

    #pragma unroll
    for (int c = 0; c < EPT; ++c) {
        int o = tid + (c << 9);
        float2 w = shw[o];
        float fm = sqrtf(fmaf(w.x, w.x, w.y * w.y));
        float den = fmaxf(fm - thr, 0.f);
        float s = den * fast_rcp(fmaxf(fm, EPSF)) * pf;
        shw[o] = make_float2(w.x * s, w.y * s);
    }
    __syncthreads();

    #pragma unroll
    for (int t = 0; t < 16; ++t) {
        int k = t - n * CNT;
        if ((unsigned)k < (unsigned)CNT) v[t] = shw[tid + (k << 9)];
    }
    __syncthreads();
}

// -------- ROOT filter fully in registers (hot path) ------------------------
__device__ __forceinline__ void filter_root_reg(
    float2 (&v)[16], int tid,
    const float* __restrict__ Wp, const float* __restrict__ bp,
    const float* __restrict__ Wo, const float* __restrict__ bo,
    const float* __restrict__ Se, const float* __restrict__ Coh,
    const int* __restrict__ fPg, int row,
    uint* hist, uint* wsum, uint* selres,
    float lfg, float sigma, float hfg, float cutoff)
{
    NodeConst nc = node_consts(0, 1, 0, 0, NN, row, Wp, bp, Wo, bo, Se, Coh,
                               lfg, sigma, hfg, cutoff);
    float invnm1 = 1.f / (float)(NN - 1);
    #pragma unroll
    for (int t = 0; t < 16; ++t) {
        int o = tid + (t << 9);
        v[t] = mlp_apply(v[t], o, 0, invnm1, nc, Wp, Wo);
    }
    float nf = median_root_reg(v, tid, hist, wsum, selres);
    float thr = (1.f - nc.hbd) * nf;
    float pf = fPg[0] ? (hfg * hfg) : 1.f;
    #pragma unroll
    for (int t = 0; t < 16; ++t) {
        float2 w = v[t];
        float fm = sqrtf(fmaf(w.x, w.x, w.y * w.y));
        float den = fmaxf(fm - thr, 0.f);
        float s = den * fast_rcp(fmaxf(fm, EPSF)) * pf;
        v[t] = make_float2(w.x * s, w.y * s);
    }
}

template<int DT>
__device__ __forceinline__ void merge_reg(float2 (&v)[16]){
    #pragma unroll
    for (int t = 0; t < 16; ++t) {
        if ((t & DT) == 0) {
            float2 lo = v[t], hi = v[t + DT];
            v[t]      = make_float2((lo.x + hi.x) * SQRT1_2F, (lo.y + hi.y) * SQRT1_2F);
            v[t + DT] = make_float2((lo.x - hi.x) * SQRT1_2F, (lo.y - hi.y) * SQRT1_2F);
        }
    }
}

// ======================= K3: apply + inverse FFT ===========================
__global__ __launch_bounds__(NT, 4) void k_rest(
    const uint* __restrict__ Lv16,
    const float* __restrict__ Se, const float* __restrict__ Coh,
    const int* __restrict__ fFg, const int* __restrict__ fPg,
    float* __restrict__ out,
    const float* __restrict__ Wp, const float* __restrict__ bp,
    const float* __restrict__ Wo, const float* __restrict__ bo,
    const float* lfg_p, const float* sig_p, const float* hfg_p, const float* cut_p)
{
    __shared__ float2 shw[4096];                // 32KB window
    __shared__ __align__(16) uint hist[1024];   // 4KB
    __shared__ uint wsum[8];
    __shared__ uint selres[2];

    int row = blockIdx.x, tid = threadIdx.x;
    float lfg = *lfg_p, sigma = *sig_p, hfg = *hfg_p, cutoff = *cut_p;

    const uint* lr = Lv16 + ((size_t)row << LOGN);
    uint raw[16];
    #pragma unroll
    for (int t = 0; t < 16; ++t) raw[t] = lr[tid + (t << 9)];

    float2 v[16];
    #pragma unroll
    for (int t = 0; t < 16; ++t) v[t] = unpack_h2(raw[t]);

    // frontier filters (leaves up to root), register merges
    for (int n = 0; n < 16; ++n)
        if (fFg[15 + n])
            filter_node_sh<4>(v, n, tid, shw, Wp, bp, Wo, bo, Se, Coh, fPg, row, hist, wsum, selres, lfg, sigma, hfg, cutoff);
    merge_reg<1>(v);
    for (int n = 0; n < 8; ++n)
        if (fFg[7 + n])
            filter_node_sh<3>(v, n, tid, shw, Wp, bp, Wo, bo, Se, Coh, fPg, row, hist, wsum, selres, lfg, sigma, hfg, cutoff);
    merge_reg<2>(v);
    for (int n = 0; n < 4; ++n)
        if (fFg[3 + n])
            filter_node_sh<2>(v, n, tid, shw, Wp, bp, Wo, bo, Se, Coh, fPg, row, hist, wsum, selres, lfg, sigma, hfg, cutoff);
    merge_reg<4>(v);
    for (int n = 0; n < 2; ++n)
        if (fFg[1 + n])
            filter_node_sh<1>(v, n, tid, shw, Wp, bp, Wo, bo, Se, Coh, fPg, row, hist, wsum, selres, lfg, sigma, hfg, cutoff);
    merge_reg<8>(v);
    if (fFg[0])
        filter_root_reg(v, tid, Wp, bp, Wo, bo, Se, Coh, fPg, row, hist, wsum, selres, lfg, sigma, hfg, cutoff);

    // ---- inverse FFT: 9 LDS levels in 2 batches, then 4 register levels ----
    #pragma unroll
    for (int b = 0; b < 2; ++b) {
        __syncthreads();
        #pragma unroll
        for (int k = 0; k < 8; ++k) shw[tid + (k << 9)] = v[8 * b + k];
        __syncthreads();
        inv_r4_batch<1, 0>(shw, tid);    // levels 1,2
        inv_r4_batch<4, 2>(shw, tid);    // levels 4,8
        inv_r4_batch<16, 4>(shw, tid);   // levels 16,32
        inv_r4_batch<64, 6>(shw, tid);   // levels 64,128
        {   // radix-2 level h=256, hoisted twiddle; 2048 pairs
            int jj = tid & 255;
            float ang = (PIF / 256.0f) * (float)jj;
            float2 W = make_float2(__cosf(ang), __sinf(ang));
            #pragma unroll
            for (int c = 0; c < 4; ++c) {
                int q = tid + (c << 9);
                int p = ((q >> 8) << 9) | jj;
                float2 a = shw[p], bb = shw[p + 256];
                float2 tb = cmul(W, bb);
                shw[p] = cadd(a, tb);
                shw[p + 256] = csub(a, tb);
            }
            __syncthreads();
        }
        #pragma unroll
        for (int k = 0; k < 8; ++k) v[8 * b + k] = shw[tid + (k << 9)];
    }

    // 4 register DIT levels (h = 512,1024,2048,4096)
    {
        float a0 = PIF * (1.0f / 4096.0f) * (float)tid;
        float2 w1 = make_float2(__cosf(a0), __sinf(a0));
        float2 w2 = cmul(w1, w1);
        float2 w4 = cmul(w2, w2);
        float2 w8 = cmul(w4, w4);
        #pragma unroll
        for (int t = 0; t < 16; ++t) if (!(t & 1)) {       // h=512
            float2 tb = cmul(w8, v[t + 1]);
            float2 a = v[t];
            v[t] = cadd(a, tb);
            v[t + 1] = csub(a, tb);
        }
        #pragma unroll
        for (int t = 0; t < 16; ++t) if (!(t & 2)) {       // h=1024
            float2 W = (t & 1) ? make_float2(-w4.y, w4.x) : w4;   // w4 * (0,+1)
            float2 tb = cmul(W, v[t + 2]);
            float2 a = v[t];
            v[t] = cadd(a, tb);
            v[t + 2] = csub(a, tb);
        }
        const float2 K8p[4] = {{1.f,0.f},{C4C,C4C},{0.f,1.f},{-C4C,C4C}};
        #pragma unroll
        for (int t = 0; t < 16; ++t) if (!(t & 4)) {       // h=2048
            float2 W = cmul(w2, K8p[t & 3]);
            float2 tb = cmul(W, v[t + 4]);
            float2 a = v[t];
            v[t] = cadd(a, tb);
            v[t + 4] = csub(a, tb);
        }
        const float2 K16p[8] = {
            { 1.f, 0.f}, { C8C, S8C}, { C4C, C4C}, { S8C, C8C},
            { 0.f, 1.f}, {-S8C, C8C}, {-C4C, C4C}, {-C8C, S8C}};
        #pragma unroll
        for (int t = 0; t < 8; ++t) {                      // h=4096
            float2 W = cmul(w1, K16p[t]);
            float2 tb = cmul(W, v[t + 8]);
            float2 a = v[t];
            v[t] = cadd(a, tb);
            v[t + 8] = csub(a, tb);
        }
    }

    // store natural order from regs
    float* orow = out + ((size_t)row << LOGN);
    #pragma unroll
    for (int t = 0; t < 16; ++t)
        orow[tid + (t << 9)] = v[t].x * (1.0f / (float)NN);
}

// ---------------- host launch ----------------------------------------------
extern "C" void kernel_launch(void* const* d_in, const int* in_sizes, int n_in,
                              void* d_out, int out_size, void* d_ws, size_t ws_size,
                              hipStream_t stream) {
    const float* x   = (const float*)d_in[0];
    const float* Wp  = (const float*)d_in[1];
    const float* bp  = (const float*)d_in[2];
    const float* Wo  = (const float*)d_in[3];
    const float* bo  = (const float*)d_in[4];
    const float* lfg = (const float*)d_in[5];
    const float* sig = (const float*)d_in[6];
    const float* hfg = (const float*)d_in[7];
    const float* cut = (const float*)d_in[8];
    float* out = (float*)d_out;

    size_t LVB = (size_t)ROWS * NN * sizeof(uint);   // 16,777,216 B (fp16x2 leaves)
    char* ws = (char*)d_ws;
    uint*   Lv16 = (uint*)ws;
    float*  Se   = (float*)(ws + LVB);
    float*  Coh  = Se  + (size_t)NNODES * ROWS;
    float*  Ent  = Coh + (size_t)NNODES * ROWS;
    int*    fFg  = (int*)(Ent + (size_t)NNODES * ROWS);
    int*    fPg  = fFg + NNODES;
    size_t need = (size_t)((char*)(fPg + NNODES) - ws);
    if (ws_size < need) return;

    dim3 b(NT);
    k_pre   <<<dim3(ROWS), b, 0, stream>>>(x, Lv16, Se, Coh, Ent, lfg, sig, hfg, cut);
    k_decide<<<dim3(1),    b, 0, stream>>>(Se, Coh, Ent, fFg, fPg);
    k_rest  <<<dim3(ROWS), b, 0, stream>>>(Lv16, Se, Coh, fFg, fPg, out, Wp, bp, Wo, bo, lfg, sig, hfg, cut);
}